// Round 3
// baseline (304.503 us; speedup 1.0000x reference)
//
#include <hip/hip_runtime.h>

#define NB   8
#define NC   64
#define H    128
#define W    128
#define TILE 16
#define HALO 18          // TILE + 2
#define ICP  72          // padded channel stride (bf16) -> 144 B; B-frag reads 2-way only

typedef __attribute__((ext_vector_type(8))) short short8;
typedef __attribute__((ext_vector_type(4))) float float4_t;

static __device__ __forceinline__ unsigned short f2bf(float f) {
    unsigned u = __builtin_bit_cast(unsigned, f);
    u += 0x7fffu + ((u >> 16) & 1u);   // round-to-nearest-even
    return (unsigned short)(u >> 16);
}

// ---------------- weights: fold 3x3 -> per-parity 2x2, MFMA A-frag order ----------------
// k = tap*64 + ic (tap=(i,j) at input offset (pr+i-1, pc+j-1));
// flat: (((p*8 + s)*4 + m)*64 + lane)*8 + jj,  s=tap*2+(ic>>5), m=oc>>4,
// lane=((ic>>3)&3)*16+(oc&15), jj=ic&7.  Total 128 KiB bf16.
__global__ void prep_weights(const float* __restrict__ w, unsigned short* __restrict__ Aw) {
    int t = blockIdx.x * blockDim.x + threadIdx.x;
    if (t >= NC * NC) return;
    int oc = t >> 6, ic = t & 63;
    const float* wp = w + (oc * NC + ic) * 9;
    float wv[3][3];
#pragma unroll
    for (int kh = 0; kh < 3; ++kh)
#pragma unroll
        for (int kw = 0; kw < 3; ++kw) wv[kh][kw] = wp[kh * 3 + kw];
    float rc[2][2][3];
#pragma unroll
    for (int kw = 0; kw < 3; ++kw) {
        rc[0][0][kw] = wv[0][kw];
        rc[0][1][kw] = wv[1][kw] + wv[2][kw];
        rc[1][0][kw] = wv[0][kw] + wv[1][kw];
        rc[1][1][kw] = wv[2][kw];
    }
    int m = oc >> 4;
    int lane = ((ic >> 3) & 3) * 16 + (oc & 15);
    int jj = ic & 7;
#pragma unroll
    for (int pr = 0; pr < 2; ++pr)
#pragma unroll
        for (int pc = 0; pc < 2; ++pc) {
            int p = pr * 2 + pc;
#pragma unroll
            for (int i = 0; i < 2; ++i)
#pragma unroll
                for (int j = 0; j < 2; ++j) {
                    float v;
                    if (pc == 0) v = (j == 0) ? rc[pr][i][0] : (rc[pr][i][1] + rc[pr][i][2]);
                    else         v = (j == 0) ? (rc[pr][i][0] + rc[pr][i][1]) : rc[pr][i][2];
                    int s = (i * 2 + j) * 2 + (ic >> 5);
                    Aw[((((size_t)(p * 8 + s) * 4 + m) * 64 + lane) * 8) + jj] = f2bf(v);
                }
        }
}

// ---------------- x: NCHW fp32 -> pixel-major channel-last bf16 via LDS transpose ----------------
// xcl[((b*H + h)*W + w)*64 + ic], one block = 64 px x 64 ic.
__global__ __launch_bounds__(256) void cvt_x(const float* __restrict__ x,
                                             unsigned* __restrict__ xcl32) {
    __shared__ float t[NC][65];
    const int tid = threadIdx.x;
    const int px0 = blockIdx.x * 64;
    const int b = blockIdx.y;
    const float* xb = x + (size_t)b * NC * H * W + px0;
    {
        const int ic4 = tid >> 6, px = tid & 63;
#pragma unroll
        for (int io = 0; io < 16; ++io) {
            int ic = io * 4 + ic4;
            t[ic][px] = xb[(size_t)ic * (H * W) + px];
        }
    }
    __syncthreads();
    {
        const int icp = tid & 31;
#pragma unroll
        for (int po = 0; po < 8; ++po) {
            int px = po * 8 + (tid >> 5);
            unsigned d = (unsigned)f2bf(t[2 * icp][px]) | ((unsigned)f2bf(t[2 * icp + 1][px]) << 16);
            xcl32[((size_t)b * (H * W) + px0 + px) * 32 + icp] = d;
        }
    }
}

// ---------------- conv: 16x16 input tile -> 32x? outputs, one batch, one row-parity ----------------
__global__ __launch_bounds__(256, 3) void upconv_mfma(
    const unsigned short* __restrict__ xcl, const unsigned short* __restrict__ Aw,
    const float* __restrict__ bias, float* __restrict__ out) {
    __shared__ __align__(16) unsigned short xs[HALO * HALO * ICP];  // 46,656 B

    const int tid = threadIdx.x;
    const int tx = blockIdx.x & 7, ty = blockIdx.x >> 3;
    const int b = blockIdx.y, pr = blockIdx.z;
    const int r0 = ty * TILE, c0 = tx * TILE;

    // ---- stage 18x18 halo x 64 ic from channel-last bf16: fully coalesced 16B chunks ----
    for (int e = tid; e < HALO * HALO * 8; e += 256) {
        int px = e >> 3, c8 = e & 7;
        int rr = px / HALO, cc = px - rr * HALO;
        int gr = r0 - 1 + rr, gc = c0 - 1 + cc;
        short8 v = (short8)0;
        if (((unsigned)gr < (unsigned)H) & ((unsigned)gc < (unsigned)W))
            v = *(const short8*)(xcl + ((size_t)b * (H * W) + (size_t)gr * W + gc) * 64 + c8 * 8);
        *(short8*)&xs[px * ICP + c8 * 8] = v;
    }
    __syncthreads();

    const int wave = tid >> 6, lane = tid & 63;
    const int tcl = lane & 15, khi = lane >> 4;

    float4_t acc[4][4][2];  // [oc-tile m][row-tile t][pc]
#pragma unroll
    for (int m = 0; m < 4; ++m)
#pragma unroll
        for (int t = 0; t < 4; ++t)
#pragma unroll
            for (int pc = 0; pc < 2; ++pc) acc[m][t][pc] = (float4_t){0.f, 0.f, 0.f, 0.f};

#pragma unroll
    for (int s = 0; s < 8; ++s) {
        const int i = s >> 2, j = (s >> 1) & 1, ich = (s & 1) * 32;
#pragma unroll
        for (int pc = 0; pc < 2; ++pc) {
            short8 Bf[4];
#pragma unroll
            for (int t = 0; t < 4; ++t) {
                int row = wave * 4 + t + pr + i;
                int col = tcl + pc + j;
                Bf[t] = *(const short8*)&xs[(row * HALO + col) * ICP + ich + khi * 8];
            }
            short8 Af[4];
#pragma unroll
            for (int m = 0; m < 4; ++m)
                Af[m] = *(const short8*)(Aw + (((size_t)((pr * 2 + pc) * 8 + s) * 4 + m) * 64 + lane) * 8);
#pragma unroll
            for (int m = 0; m < 4; ++m)
#pragma unroll
                for (int t = 0; t < 4; ++t)
                    acc[m][t][pc] = __builtin_amdgcn_mfma_f32_16x16x32_bf16(
                        Af[m], Bf[t], acc[m][t][pc], 0, 0, 0);
        }
    }

    // ---- epilogue: +bias, float2 stores ----
#pragma unroll
    for (int m = 0; m < 4; ++m)
#pragma unroll
        for (int t = 0; t < 4; ++t) {
            const int orow = 2 * (r0 + wave * 4 + t) + pr;
#pragma unroll
            for (int reg = 0; reg < 4; ++reg) {
                const int oc = m * 16 + khi * 4 + reg;
                const float bv = bias[oc];
                float2 v = make_float2(acc[m][t][0][reg] + bv, acc[m][t][1][reg] + bv);
                size_t idx = (((size_t)(b * NC + oc) * 256 + orow) * 256) + 2 * (c0 + tcl);
                *reinterpret_cast<float2*>(out + idx) = v;
            }
        }
}

extern "C" void kernel_launch(void* const* d_in, const int* in_sizes, int n_in,
                              void* d_out, int out_size, void* d_ws, size_t ws_size,
                              hipStream_t stream) {
    const float* x    = (const float*)d_in[0];
    const float* wgt  = (const float*)d_in[1];
    const float* bias = (const float*)d_in[2];
    float* out = (float*)d_out;
    unsigned short* Aw  = (unsigned short*)d_ws;                    // 128 KiB
    unsigned short* xcl = (unsigned short*)((char*)d_ws + (64 * 64 * 16) * 2);  // 16.8 MB

    prep_weights<<<dim3(16), dim3(256), 0, stream>>>(wgt, Aw);
    cvt_x<<<dim3(256, NB), dim3(256), 0, stream>>>(x, (unsigned*)xcl);
    upconv_mfma<<<dim3(64, NB, 2), dim3(256), 0, stream>>>(xcl, Aw, bias, out);
}

// Round 4
// 208.987 us; speedup vs baseline: 1.4570x; 1.4570x over previous
//
#include <hip/hip_runtime.h>

#define NB   8
#define NC   64
#define H    128
#define W    128
#define TILE 16

typedef __attribute__((ext_vector_type(8))) short short8;
typedef __attribute__((ext_vector_type(4))) float float4_t;

static __device__ __forceinline__ unsigned short f2bf(float f) {
    unsigned u = __builtin_bit_cast(unsigned, f);
    u += 0x7fffu + ((u >> 16) & 1u);   // round-to-nearest-even
    return (unsigned short)(u >> 16);
}

// ---------------- weights: fold 3x3 -> per-parity 2x2, MFMA A-frag order ----------------
// k = tap*64 + ic (tap=(i,j) at input offset (pr+i-1, pc+j-1));
// flat: (((p*8 + s)*4 + m)*64 + lane)*8 + jj,  s=tap*2+(ic>>5), m=oc>>4,
// lane=((ic>>3)&3)*16+(oc&15), jj=ic&7.  Total 128 KiB bf16.
__global__ void prep_weights(const float* __restrict__ w, unsigned short* __restrict__ Aw) {
    int t = blockIdx.x * blockDim.x + threadIdx.x;
    if (t >= NC * NC) return;
    int oc = t >> 6, ic = t & 63;
    const float* wp = w + (oc * NC + ic) * 9;
    float wv[3][3];
#pragma unroll
    for (int kh = 0; kh < 3; ++kh)
#pragma unroll
        for (int kw = 0; kw < 3; ++kw) wv[kh][kw] = wp[kh * 3 + kw];
    float rc[2][2][3];
#pragma unroll
    for (int kw = 0; kw < 3; ++kw) {
        rc[0][0][kw] = wv[0][kw];
        rc[0][1][kw] = wv[1][kw] + wv[2][kw];
        rc[1][0][kw] = wv[0][kw] + wv[1][kw];
        rc[1][1][kw] = wv[2][kw];
    }
    int m = oc >> 4;
    int lane = ((ic >> 3) & 3) * 16 + (oc & 15);
    int jj = ic & 7;
#pragma unroll
    for (int pr = 0; pr < 2; ++pr)
#pragma unroll
        for (int pc = 0; pc < 2; ++pc) {
            int p = pr * 2 + pc;
#pragma unroll
            for (int i = 0; i < 2; ++i)
#pragma unroll
                for (int j = 0; j < 2; ++j) {
                    float v;
                    if (pc == 0) v = (j == 0) ? rc[pr][i][0] : (rc[pr][i][1] + rc[pr][i][2]);
                    else         v = (j == 0) ? (rc[pr][i][0] + rc[pr][i][1]) : rc[pr][i][2];
                    int s = (i * 2 + j) * 2 + (ic >> 5);
                    Aw[((((size_t)(p * 8 + s) * 4 + m) * 64 + lane) * 8) + jj] = f2bf(v);
                }
        }
}

// ---------------- x: NCHW fp32 -> pixel-major channel-last bf16 (same as round 3) ----------------
// xcl[((b*H + h)*W + w)*64 + ic]
__global__ __launch_bounds__(256) void cvt_x(const float* __restrict__ x,
                                             unsigned* __restrict__ xcl32) {
    __shared__ float t[NC][65];
    const int tid = threadIdx.x;
    const int px0 = blockIdx.x * 64;
    const int b = blockIdx.y;
    const float* xb = x + (size_t)b * NC * H * W + px0;
    {
        const int ic4 = tid >> 6, px = tid & 63;
#pragma unroll
        for (int io = 0; io < 16; ++io) {
            int ic = io * 4 + ic4;
            t[ic][px] = xb[(size_t)ic * (H * W) + px];
        }
    }
    __syncthreads();
    {
        const int icp = tid & 31;
#pragma unroll
        for (int po = 0; po < 8; ++po) {
            int px = po * 8 + (tid >> 5);
            unsigned d = (unsigned)f2bf(t[2 * icp][px]) | ((unsigned)f2bf(t[2 * icp + 1][px]) << 16);
            xcl32[((size_t)b * (H * W) + px0 + px) * 32 + icp] = d;
        }
    }
}

// ---------------- conv: LDS-free, latency-lean ----------------
// grid.x = b + 8*tile (batch pinned to XCD for L2 residency of its 2 MB slice)
// grid.z = pr*2 + ocg (row parity x 32-oc group)
// wave: 4 pixel-rows x 32 oc x both col parities; acc[2][4][2] float4 = 64 VGPRs.
__global__ __launch_bounds__(256, 4) void upconv_mfma(
    const unsigned short* __restrict__ xcl, const unsigned short* __restrict__ Aw,
    const float* __restrict__ bias, float* __restrict__ out) {
    const int tid = threadIdx.x;
    const int wave = tid >> 6, lane = tid & 63;
    const int tcl = lane & 15, khi = lane >> 4;

    const int bx = blockIdx.x;
    const int b = bx & 7, tile = bx >> 3;
    const int tx = tile & 7, ty = tile >> 3;
    const int r0 = ty * TILE, c0 = tx * TILE;
    const int z = blockIdx.z, pr = z >> 1, ocg = z & 1;
    const bool edge = (tx == 0) | (tx == 7);

    const unsigned short* xb = xcl + (size_t)b * (H * W) * 64;
    const int laneB = tcl * 64 + khi * 8;  // shorts within a pixel-row
    const int rbase = r0 + wave * 4 + pr - 1;

    float4_t acc[2][4][2];
#pragma unroll
    for (int m = 0; m < 2; ++m)
#pragma unroll
        for (int t = 0; t < 4; ++t)
#pragma unroll
            for (int pc = 0; pc < 2; ++pc) acc[m][t][pc] = (float4_t){0.f, 0.f, 0.f, 0.f};

#pragma unroll
    for (int i = 0; i < 2; ++i) {
#pragma unroll
        for (int ich = 0; ich < 2; ++ich) {
            // hoist A-frags for this (i, ich): 8 frags = 32 VGPRs
            short8 Af[2][2][2];  // [j][pc][m]
#pragma unroll
            for (int j = 0; j < 2; ++j)
#pragma unroll
                for (int pc = 0; pc < 2; ++pc)
#pragma unroll
                    for (int m = 0; m < 2; ++m) {
                        int s = (i * 2 + j) * 2 + ich;
                        int p = pr * 2 + pc;
                        Af[j][pc][m] = *(const short8*)(
                            Aw + (((size_t)(p * 8 + s) * 4 + (ocg * 2 + m)) * 64 + lane) * 8);
                    }
#pragma unroll
            for (int t = 0; t < 4; ++t) {
                const int row = rbase + t + i;
                if ((unsigned)row < (unsigned)H) {  // wave-uniform
                    const unsigned short* rp = xb + (size_t)row * (W * 64);
                    short8 Bs[3];  // col shifts 0,1,2 (shift 1 shared by pc0/j1 and pc1/j0)
#pragma unroll
                    for (int sh = 0; sh < 3; ++sh) {
                        if (!edge) {
                            Bs[sh] = *(const short8*)(rp + (c0 - 1 + sh) * 64 + laneB + ich * 32);
                        } else {
                            int gc = c0 - 1 + sh + tcl;
                            int gcc = gc < 0 ? 0 : (gc > W - 1 ? W - 1 : gc);
                            short8 v = *(const short8*)(rp + gcc * 64 + khi * 8 + ich * 32);
                            if ((unsigned)gc >= (unsigned)W) v = (short8)0;
                            Bs[sh] = v;
                        }
                    }
#pragma unroll
                    for (int pc = 0; pc < 2; ++pc)
#pragma unroll
                        for (int j = 0; j < 2; ++j)
#pragma unroll
                            for (int m = 0; m < 2; ++m)
                                acc[m][t][pc] = __builtin_amdgcn_mfma_f32_16x16x32_bf16(
                                    Af[j][pc][m], Bs[pc + j], acc[m][t][pc], 0, 0, 0);
                }
            }
        }
    }

    // ---- epilogue: +bias, float2 stores ----
#pragma unroll
    for (int m = 0; m < 2; ++m) {
        const int ocb = (ocg * 2 + m) * 16 + khi * 4;
        const float4_t bv = *(const float4_t*)(bias + ocb);
#pragma unroll
        for (int t = 0; t < 4; ++t) {
            const int orow = 2 * (r0 + wave * 4 + t) + pr;
#pragma unroll
            for (int reg = 0; reg < 4; ++reg) {
                float2 v = make_float2(acc[m][t][0][reg] + bv[reg],
                                       acc[m][t][1][reg] + bv[reg]);
                size_t idx = (((size_t)(b * NC + ocb + reg) * 256 + orow) * 256) + 2 * (c0 + tcl);
                *reinterpret_cast<float2*>(out + idx) = v;
            }
        }
    }
}

extern "C" void kernel_launch(void* const* d_in, const int* in_sizes, int n_in,
                              void* d_out, int out_size, void* d_ws, size_t ws_size,
                              hipStream_t stream) {
    const float* x    = (const float*)d_in[0];
    const float* wgt  = (const float*)d_in[1];
    const float* bias = (const float*)d_in[2];
    float* out = (float*)d_out;
    unsigned short* Aw  = (unsigned short*)d_ws;                                 // 128 KiB
    unsigned short* xcl = (unsigned short*)((char*)d_ws + (64 * 64 * 16) * 2);   // 16.8 MB

    prep_weights<<<dim3(16), dim3(256), 0, stream>>>(wgt, Aw);
    cvt_x<<<dim3(256, NB), dim3(256), 0, stream>>>(x, (unsigned*)xcl);
    upconv_mfma<<<dim3(8 * 64, 1, 4), dim3(256), 0, stream>>>(xcl, Aw, bias, out);
}